// Round 5
// baseline (285.701 us; speedup 1.0000x reference)
//
#include <hip/hip_runtime.h>

#define HW 96
#define NPIX 9216
#define QN 192
#define ASTRIDE 52
#define SCALE 0.17677669529663687f
#define NT 576

// XOR-swizzled LDS word addresses (linear rows of 64 words).
__device__ __forceinline__ int xswz(int row, int col) {
    return row * 64 + (((col & 60) ^ (((row >> 2) & 7) << 2)) | (col & 3));
}
__device__ __forceinline__ int wswz(int row, int col) {
    return row * 64 + (((col & 60) ^ ((row & 7) << 2)) | (col & 3));
}

// 18px x 192j x 64c GEMM from LDS. 576 threads: pxg=t%9 (2 px), jo=t/9 (3 j).
__device__ __forceinline__ void qkv_gemm(const float* __restrict__ xs,
                                         const float* __restrict__ ws,
                                         const float* __restrict__ qb,
                                         float* __restrict__ qkv,
                                         int i0, int j0c, int t)
{
    const int pxg = t % 9, jo = t / 9;
    const int jb = jo * 3;
    float acc[2][3];
    #pragma unroll
    for (int jj = 0; jj < 3; ++jj) {
        float bv = qb[jb + jj];
        acc[0][jj] = bv; acc[1][jj] = bv;
    }
    #pragma unroll
    for (int cc = 0; cc < 16; ++cc) {
        float4 xv[2], wv[3];
        #pragma unroll
        for (int ii = 0; ii < 2; ++ii)
            xv[ii] = *(const float4*)&xs[xswz(pxg * 2 + ii, cc * 4)];
        #pragma unroll
        for (int jj = 0; jj < 3; ++jj)
            wv[jj] = *(const float4*)&ws[wswz(jb + jj, cc * 4)];
        #pragma unroll
        for (int ii = 0; ii < 2; ++ii)
            #pragma unroll
            for (int jj = 0; jj < 3; ++jj) {
                acc[ii][jj] = fmaf(xv[ii].x, wv[jj].x, acc[ii][jj]);
                acc[ii][jj] = fmaf(xv[ii].y, wv[jj].y, acc[ii][jj]);
                acc[ii][jj] = fmaf(xv[ii].z, wv[jj].z, acc[ii][jj]);
                acc[ii][jj] = fmaf(xv[ii].w, wv[jj].w, acc[ii][jj]);
            }
    }
    #pragma unroll
    for (int ii = 0; ii < 2; ++ii) {
        int px = pxg * 2 + ii;
        float* o = qkv + ((i0 + px / 3) * HW + j0c + px % 3) * QN + jb;
        o[0] = acc[ii][0]; o[1] = acc[ii][1]; o[2] = acc[ii][2];
    }
}

__global__ __launch_bounds__(NT, 5) void k_qkv0(const float* __restrict__ x,
                                                const float* __restrict__ qw,
                                                const float* __restrict__ qb,
                                                float* __restrict__ qkv)
{
    __shared__ float xs[18 * 64];
    __shared__ float ws[QN * 64];
    const int t = threadIdx.x;
    const int i0 = (blockIdx.x >> 5) * 6, j0c = (blockIdx.x & 31) * 3;
    #pragma unroll
    for (int it = 0; it < 2; ++it) {
        int l = it * NT + t;
        int px = l % 18, c = l / 18;
        xs[xswz(px, c)] = x[c * NPIX + (i0 + px / 3) * HW + j0c + px % 3];
    }
    #pragma unroll
    for (int it = 0; it < 6; ++it) {
        int l = it * NT + t;
        if (l < 3072) {
            int j = l >> 4, cs = (l & 15) << 2;
            *(float4*)&ws[wswz(j, cs)] = *(const float4*)&qw[j * 64 + cs];
        }
    }
    __syncthreads();
    qkv_gemm(xs, ws, qb, qkv, i0, j0c, t);
}

// Fused stage. Attention: 36 groups (18 px x 2 h) x 16 lanes.
//   QK neighbor-split: lane ln owns n = {ln, 16+ln, 32+ln, 48+ln} (masked > 48),
//   full 32-dim dots, Q from LDS tile (broadcast). Softmax: 4 local + xor1/2/4/8.
//   Weights -> LDS table att_s[g][52] (same-wave ds ordering, no barrier),
//   PV dim-split: lane owns 2 dims, weights via broadcast b128 reads.
template <int HASPREV, int LAST>
__global__ __launch_bounds__(NT, 5) void k_stage(const float* __restrict__ qkv,
                                                 const float* __restrict__ rpb,
                                                 const float* __restrict__ prev,
                                                 float* __restrict__ cur,
                                                 const float* __restrict__ pw,
                                                 const float* __restrict__ pb,
                                                 const float* __restrict__ qw,
                                                 const float* __restrict__ qb,
                                                 float* __restrict__ qkvn,
                                                 float* __restrict__ outp)
{
    __shared__ float xs[18 * 64];
    __shared__ float ws[QN * 64];
    __shared__ float qs_s[36 * 32];
    __shared__ float att_s[36 * 52];
    const int t = threadIdx.x;
    const int i0 = (blockIdx.x >> 5) * 6, j0c = (blockIdx.x & 31) * 3;
    // stage proj weights (consumed after barrier 2)
    #pragma unroll
    for (int it = 0; it < 2; ++it) {
        int l = it * NT + t;
        if (l < 1024) {
            int j = l >> 4, cs = (l & 15) << 2;
            *(float4*)&ws[wswz(j, cs)] = *(const float4*)&pw[j * 64 + cs];
        }
    }
    // stage Q tile (linear; reads are 16-lane broadcast -> bank-free)
    if (t < 288) {
        int gq = t >> 3, dc = t & 7;
        int hq = gq & 1, plq = gq >> 1;
        int pq = (i0 + plq / 3) * HW + j0c + plq % 3;
        *(float4*)&qs_s[gq * 32 + dc * 4] =
            *(const float4*)&qkv[pq * QN + hq * 32 + dc * 4];
    }
    __syncthreads();
    // ---------------- attention ----------------
    const int ln = t & 15, g = t >> 4;
    const int h = g & 1, pl = g >> 1;
    const int i = i0 + pl / 3, jx = j0c + pl % 3;
    const int p = i * HW + jx;
    int si = i - 3;  si = si < 0 ? 0 : (si > 89 ? 89 : si);
    int sj = jx - 3; sj = sj < 0 ? 0 : (sj > 89 ? 89 : sj);
    const float* kb = qkv + (si * HW + sj) * QN + 64 + h * 32;
    // owned-neighbor K row pointers
    const float* kp[4];
    int aa[4], bb[4];
    #pragma unroll
    for (int k = 0; k < 4; ++k) {
        int n = (k << 4) | ln;
        int a = (n * 147) >> 10;
        int b = n - a * 7;
        aa[k] = a; bb[k] = b;
        kp[k] = kb + (a * HW + b) * QN;
    }
    float s0 = 0.f, s1 = 0.f, s2 = 0.f, s3 = 0.f;
    #pragma unroll
    for (int dc = 0; dc < 8; ++dc) {
        float4 qv = *(const float4*)&qs_s[g * 32 + dc * 4];
        float4 k0 = *(const float4*)&kp[0][dc * 4];
        float4 k1 = *(const float4*)&kp[1][dc * 4];
        float4 k2 = *(const float4*)&kp[2][dc * 4];
        float4 k3 = *(const float4*)&kp[3][dc * 4];
        s0 = fmaf(qv.x, k0.x, s0); s0 = fmaf(qv.y, k0.y, s0);
        s0 = fmaf(qv.z, k0.z, s0); s0 = fmaf(qv.w, k0.w, s0);
        s1 = fmaf(qv.x, k1.x, s1); s1 = fmaf(qv.y, k1.y, s1);
        s1 = fmaf(qv.z, k1.z, s1); s1 = fmaf(qv.w, k1.w, s1);
        s2 = fmaf(qv.x, k2.x, s2); s2 = fmaf(qv.y, k2.y, s2);
        s2 = fmaf(qv.z, k2.z, s2); s2 = fmaf(qv.w, k2.w, s2);
        s3 = fmaf(qv.x, k3.x, s3); s3 = fmaf(qv.y, k3.y, s3);
        s3 = fmaf(qv.z, k3.z, s3); s3 = fmaf(qv.w, k3.w, s3);
    }
    float lg[4] = {s0, s1, s2, s3};
    {
        const float* rp = rpb + h * 169;
        const int rbase = (si - i + 6) * 13 + (sj - jx + 6);
        const int gp = p * 2 + h;
        #pragma unroll
        for (int k = 0; k < 4; ++k) {
            int n = (k << 4) | ln;
            int ok = (n <= 48);
            int bidx = ok ? (rbase + aa[k] * 13 + bb[k]) : 0;
            float bv = rp[bidx];
            float pv = 0.f;
            if (HASPREV) pv = prev[gp * ASTRIDE + (ok ? n : 0)];
            float l2 = fmaf(lg[k], SCALE, bv + pv);
            lg[k] = ok ? l2 : -1e30f;
        }
    }
    // softmax across 16 lanes (each lane <=4 logits)
    float mx = fmaxf(fmaxf(lg[0], lg[1]), fmaxf(lg[2], lg[3]));
    mx = fmaxf(mx, __shfl_xor(mx, 1));
    mx = fmaxf(mx, __shfl_xor(mx, 2));
    mx = fmaxf(mx, __shfl_xor(mx, 4));
    mx = fmaxf(mx, __shfl_xor(mx, 8));
    float wk[4];
    float sum = 0.f;
    #pragma unroll
    for (int k = 0; k < 4; ++k) { wk[k] = expf(lg[k] - mx); sum += wk[k]; }
    sum += __shfl_xor(sum, 1);
    sum += __shfl_xor(sum, 2);
    sum += __shfl_xor(sum, 4);
    sum += __shfl_xor(sum, 8);
    const float inv = 1.f / sum;
    wk[0] *= inv; wk[1] *= inv; wk[2] *= inv; wk[3] *= inv;
    // publish weights to the group table (same wave -> ordered, no barrier)
    att_s[g * ASTRIDE + ln]      = wk[0];
    att_s[g * ASTRIDE + 16 + ln] = wk[1];
    att_s[g * ASTRIDE + 32 + ln] = wk[2];
    if (ln == 0) att_s[g * ASTRIDE + 48] = wk[3];
    // PV: lane owns dims {ln*2, ln*2+1}
    {
        const float* vb = qkv + (si * HW + sj) * QN + 128 + h * 32 + ln * 2;
        float a0 = 0.f, a1 = 0.f;
        #pragma unroll
        for (int kk = 0; kk < 12; ++kk) {
            float4 w4 = *(const float4*)&att_s[g * ASTRIDE + kk * 4];
            #pragma unroll
            for (int c = 0; c < 4; ++c) {
                int n = kk * 4 + c;
                int a = n / 7, b = n % 7;
                float w = (&w4.x)[c];
                float2 v = *(const float2*)&vb[(a * HW + b) * QN];
                a0 = fmaf(w, v.x, a0); a1 = fmaf(w, v.y, a1);
            }
        }
        {
            float w = att_s[g * ASTRIDE + 48];
            float2 v = *(const float2*)&vb[(6 * HW + 6) * QN];
            a0 = fmaf(w, v.x, a0); a1 = fmaf(w, v.y, a1);
        }
        *(float2*)&xs[xswz(pl, h * 32 + ln * 2)] = make_float2(a0, a1);
    }
    // persist attention map for next stage
    if (!LAST) {
        const int gp = p * 2 + h;
        if (ln < 12)
            *(float4*)&cur[gp * ASTRIDE + ln * 4] =
                *(const float4*)&att_s[g * ASTRIDE + ln * 4];
        else if (ln == 12)
            cur[gp * ASTRIDE + 48] = att_s[g * ASTRIDE + 48];
    }
    __syncthreads();                      // attn tile in xs, ws staged
    // ---------------- proj: pxg=t%9 (2 px), jo=t/9 (1 j) ----------------
    const int pxg = t % 9, jo = t / 9;
    float pa0 = pb[jo], pa1 = pa0;
    #pragma unroll
    for (int cc = 0; cc < 16; ++cc) {
        float4 xv0 = *(const float4*)&xs[xswz(pxg * 2, cc * 4)];
        float4 xv1 = *(const float4*)&xs[xswz(pxg * 2 + 1, cc * 4)];
        float4 wv  = *(const float4*)&ws[wswz(jo, cc * 4)];
        pa0 = fmaf(xv0.x, wv.x, pa0); pa0 = fmaf(xv0.y, wv.y, pa0);
        pa0 = fmaf(xv0.z, wv.z, pa0); pa0 = fmaf(xv0.w, wv.w, pa0);
        pa1 = fmaf(xv1.x, wv.x, pa1); pa1 = fmaf(xv1.y, wv.y, pa1);
        pa1 = fmaf(xv1.z, wv.z, pa1); pa1 = fmaf(xv1.w, wv.w, pa1);
    }
    __syncthreads();                      // all proj reads done
    xs[xswz(pxg * 2, jo)]     = pa0;
    xs[xswz(pxg * 2 + 1, jo)] = pa1;
    if (!LAST) {
        #pragma unroll
        for (int it = 0; it < 6; ++it) {
            int l = it * NT + t;
            if (l < 3072) {
                int j = l >> 4, cs = (l & 15) << 2;
                *(float4*)&ws[wswz(j, cs)] = *(const float4*)&qw[j * 64 + cs];
            }
        }
    }
    __syncthreads();                      // xh in xs, next weights in ws
    if (LAST) {
        #pragma unroll
        for (int it = 0; it < 2; ++it) {
            int l = it * NT + t;
            int px = l % 18, c = l / 18;
            outp[c * NPIX + (i0 + px / 3) * HW + j0c + px % 3] = xs[xswz(px, c)];
        }
        return;
    }
    qkv_gemm(xs, ws, qb, qkvn, i0, j0c, t);
}

extern "C" void kernel_launch(void* const* d_in, const int* in_sizes, int n_in,
                              void* d_out, int out_size, void* d_ws, size_t ws_size,
                              hipStream_t stream)
{
    const float* x   = (const float*)d_in[0];
    const float* qw  = (const float*)d_in[1];   // (3,192,64)
    const float* qb  = (const float*)d_in[2];   // (3,192)
    const float* pw  = (const float*)d_in[3];   // (3,64,64)
    const float* pb  = (const float*)d_in[4];   // (3,64)
    const float* rpb = (const float*)d_in[5];   // (3,2,13,13)
    float* out = (float*)d_out;
    float* ws  = (float*)d_ws;

    float* qkvA = ws;                    // 1,769,472 floats
    float* qkvB = qkvA + 1769472;        // 1,769,472
    float* attA = qkvB + 1769472;        //   958,464 (18432 * 52)
    float* attB = attA + 958464;         //   958,464  (~21.8 MB total)

    k_qkv0<<<512, NT, 0, stream>>>(x, qw, qb, qkvA);
    k_stage<0, 0><<<512, NT, 0, stream>>>(qkvA, rpb,       nullptr, attA,
                                          pw,        pb,       qw + 12288, qb + 192, qkvB, nullptr);
    k_stage<1, 0><<<512, NT, 0, stream>>>(qkvB, rpb + 338, attA,    attB,
                                          pw + 4096, pb + 64,  qw + 24576, qb + 384, qkvA, nullptr);
    k_stage<1, 1><<<512, NT, 0, stream>>>(qkvA, rpb + 676, attB,    nullptr,
                                          pw + 8192, pb + 128, nullptr,    nullptr,  nullptr, out);
}

// Round 7
// 156.870 us; speedup vs baseline: 1.8213x; 1.8213x over previous
//
#include <hip/hip_runtime.h>

#define HW 96
#define NPIX 9216
#define QN 192
#define ASTRIDE 52
#define SCALE 0.17677669529663687f
#define NT 576
#define HALO_N 132          // 12 rows x 11 cols

// Unified XOR-swizzled LDS word address: linear rows of 64 words,
// 16B slot XOR'd by row&7 -> strided row access spreads across banks.
__device__ __forceinline__ int swz(int row, int col) {
    return row * 64 + (col ^ ((row & 7) << 2));
}

// halo slot hp (0..131) -> clamped global pixel index
__device__ __forceinline__ int halo_pix(int hp, int hr0, int hc0) {
    int hi = (hp * 745) >> 13;            // hp / 11 for hp < 8192
    int hj = hp - hi * 11;
    int gi = hr0 + hi; gi = gi < 0 ? 0 : (gi > 95 ? 95 : gi);
    int gj = hc0 + hj; gj = gj < 0 ? 0 : (gj > 95 ? 95 : gj);
    return gi * HW + gj;
}

// 18px x 192j x 64c GEMM from LDS. 576 thr: pxg=t%9 (2 px), jo=t/9 (3 j).
__device__ __forceinline__ void qkv_gemm(const float* __restrict__ xs,
                                         const float* __restrict__ ws,
                                         const float* __restrict__ qb,
                                         float* __restrict__ qkv,
                                         int i0, int j0c, int t)
{
    const int pxg = t % 9, jo = t / 9;
    const int jb = jo * 3;
    float acc[2][3];
    #pragma unroll
    for (int jj = 0; jj < 3; ++jj) {
        float bv = qb[jb + jj];
        acc[0][jj] = bv; acc[1][jj] = bv;
    }
    #pragma unroll
    for (int cc = 0; cc < 16; ++cc) {
        float4 xv[2], wv[3];
        #pragma unroll
        for (int ii = 0; ii < 2; ++ii)
            xv[ii] = *(const float4*)&xs[swz(pxg * 2 + ii, cc * 4)];
        #pragma unroll
        for (int jj = 0; jj < 3; ++jj)
            wv[jj] = *(const float4*)&ws[swz(jb + jj, cc * 4)];
        #pragma unroll
        for (int ii = 0; ii < 2; ++ii)
            #pragma unroll
            for (int jj = 0; jj < 3; ++jj) {
                acc[ii][jj] = fmaf(xv[ii].x, wv[jj].x, acc[ii][jj]);
                acc[ii][jj] = fmaf(xv[ii].y, wv[jj].y, acc[ii][jj]);
                acc[ii][jj] = fmaf(xv[ii].z, wv[jj].z, acc[ii][jj]);
                acc[ii][jj] = fmaf(xv[ii].w, wv[jj].w, acc[ii][jj]);
            }
    }
    #pragma unroll
    for (int ii = 0; ii < 2; ++ii) {
        int px = pxg * 2 + ii;
        float* o = qkv + ((i0 + px / 3) * HW + j0c + px % 3) * QN + jb;
        o[0] = acc[ii][0]; o[1] = acc[ii][1]; o[2] = acc[ii][2];
    }
}

__global__ __launch_bounds__(NT, 5) void k_qkv0(const float* __restrict__ x,
                                                const float* __restrict__ qw,
                                                const float* __restrict__ qb,
                                                float* __restrict__ qkv)
{
    __shared__ float xs[18 * 64];
    __shared__ float ws[QN * 64];
    const int t = threadIdx.x;
    const int tile = ((blockIdx.x & 7) << 6) | (blockIdx.x >> 3);
    const int i0 = (tile >> 5) * 6, j0c = (tile & 31) * 3;
    #pragma unroll
    for (int it = 0; it < 2; ++it) {
        int l = it * NT + t;
        int px = l % 18, c = l / 18;
        xs[swz(px, c)] = x[c * NPIX + (i0 + px / 3) * HW + j0c + px % 3];
    }
    #pragma unroll
    for (int it = 0; it < 6; ++it) {
        int l = it * NT + t;
        if (l < 3072) {
            int j = l >> 4, cs = (l & 15) << 2;
            *(float4*)&ws[swz(j, cs)] = *(const float4*)&qw[j * 64 + cs];
        }
    }
    __syncthreads();
    qkv_gemm(xs, ws, qb, qkv, i0, j0c, t);
}

// Fused stage with LDS-staged K/V halos.
// 36 groups (18 px x 2 h) x 16 lanes; lane owns 4 neighbor slots (QK) and
// 2 output dims (PV).
template <int HASPREV, int LAST>
__global__ __launch_bounds__(NT, 5) void k_stage(const float* __restrict__ qkv,
                                                 const float* __restrict__ rpb,
                                                 const float* __restrict__ prev,
                                                 float* __restrict__ cur,
                                                 const float* __restrict__ pw,
                                                 const float* __restrict__ pb,
                                                 const float* __restrict__ qw,
                                                 const float* __restrict__ qb,
                                                 float* __restrict__ qkvn,
                                                 float* __restrict__ outp)
{
    __shared__ float big[12288];          // K-halo | V-halo | pw | qw (phased)
    __shared__ float qs_s[36 * 32];
    __shared__ float att_s[36 * ASTRIDE];
    __shared__ float xs[18 * 64];
    const int t = threadIdx.x;
    const int tile = ((blockIdx.x & 7) << 6) | (blockIdx.x >> 3);
    const int i0 = (tile >> 5) * 6, j0c = (tile & 31) * 3;
    const int hr0 = i0 - 3, hc0 = j0c - 4;

    // ---- phase 1: stage K-halo (coalesced) + Q tile ----
    #pragma unroll
    for (int it = 0; it < 4; ++it) {
        int hp = it * 36 + (t >> 4);
        if (hp < HALO_N) {
            int c4 = (t & 15) << 2;
            *(float4*)&big[swz(hp, c4)] =
                *(const float4*)&qkv[halo_pix(hp, hr0, hc0) * QN + 64 + c4];
        }
    }
    if (t < 288) {
        int gq = t >> 3, dc = (t & 7) << 2;
        int hq = gq & 1, plq = gq >> 1;
        int pq = (i0 + plq / 3) * HW + j0c + plq % 3;
        *(float4*)&qs_s[gq * 32 + dc] = *(const float4*)&qkv[pq * QN + hq * 32 + dc];
    }
    __syncthreads();                                            // B1
    // ---- QK (LDS) ----
    const int ln = t & 15, g = t >> 4;
    const int h = g & 1, pl = g >> 1;
    const int i = i0 + pl / 3, jx = j0c + pl % 3;
    const int p = i * HW + jx;
    int si = i - 3;  si = si < 0 ? 0 : (si > 89 ? 89 : si);
    int sj = jx - 3; sj = sj < 0 ? 0 : (sj > 89 ? 89 : sj);
    const int hbase = (si - hr0) * 11 + (sj - hc0);
    int hofs[4], aa[4], bb[4], okm[4];
    #pragma unroll
    for (int k = 0; k < 4; ++k) {
        int n = (k << 4) | ln;
        okm[k] = (n <= 48);
        int nn = okm[k] ? n : 0;
        int a = (nn * 147) >> 10;                 // nn / 7
        int b = nn - a * 7;
        aa[k] = a; bb[k] = b;
        hofs[k] = hbase + a * 11 + b;
    }
    float s0 = 0.f, s1 = 0.f, s2 = 0.f, s3 = 0.f;
    #pragma unroll
    for (int dc = 0; dc < 8; ++dc) {
        float4 qv = *(const float4*)&qs_s[g * 32 + dc * 4];
        float4 k0 = *(const float4*)&big[swz(hofs[0], dc * 4)];
        float4 k1 = *(const float4*)&big[swz(hofs[1], dc * 4)];
        float4 k2 = *(const float4*)&big[swz(hofs[2], dc * 4)];
        float4 k3 = *(const float4*)&big[swz(hofs[3], dc * 4)];
        s0 = fmaf(qv.x, k0.x, s0); s0 = fmaf(qv.y, k0.y, s0);
        s0 = fmaf(qv.z, k0.z, s0); s0 = fmaf(qv.w, k0.w, s0);
        s1 = fmaf(qv.x, k1.x, s1); s1 = fmaf(qv.y, k1.y, s1);
        s1 = fmaf(qv.z, k1.z, s1); s1 = fmaf(qv.w, k1.w, s1);
        s2 = fmaf(qv.x, k2.x, s2); s2 = fmaf(qv.y, k2.y, s2);
        s2 = fmaf(qv.z, k2.z, s2); s2 = fmaf(qv.w, k2.w, s2);
        s3 = fmaf(qv.x, k3.x, s3); s3 = fmaf(qv.y, k3.y, s3);
        s3 = fmaf(qv.w, k3.w, s3); s3 = fmaf(qv.z, k3.z, s3);
    }
    float lg[4] = {s0, s1, s2, s3};
    {
        const float* rp = rpb + h * 169;
        const int rbase = (si - i + 6) * 13 + (sj - jx + 6);
        const int gp = p * 2 + h;
        #pragma unroll
        for (int k = 0; k < 4; ++k) {
            float bv = rp[rbase + aa[k] * 13 + bb[k]];
            float pv = 0.f;
            if (HASPREV) pv = prev[gp * ASTRIDE + ((k << 4) | ln)];
            float l2 = fmaf(lg[k], SCALE, bv + (okm[k] ? pv : 0.f));
            lg[k] = okm[k] ? l2 : -1e30f;
        }
    }
    float mx = fmaxf(fmaxf(lg[0], lg[1]), fmaxf(lg[2], lg[3]));
    mx = fmaxf(mx, __shfl_xor(mx, 1));
    mx = fmaxf(mx, __shfl_xor(mx, 2));
    mx = fmaxf(mx, __shfl_xor(mx, 4));
    mx = fmaxf(mx, __shfl_xor(mx, 8));
    float wk[4];
    float sum = 0.f;
    #pragma unroll
    for (int k = 0; k < 4; ++k) { wk[k] = expf(lg[k] - mx); sum += wk[k]; }
    sum += __shfl_xor(sum, 1);
    sum += __shfl_xor(sum, 2);
    sum += __shfl_xor(sum, 4);
    sum += __shfl_xor(sum, 8);
    const float inv = 1.f / sum;
    wk[0] *= inv; wk[1] *= inv; wk[2] *= inv; wk[3] *= inv;
    // publish weights to group table (same wave -> ordered without barrier)
    att_s[g * ASTRIDE + ln]      = wk[0];
    att_s[g * ASTRIDE + 16 + ln] = wk[1];
    att_s[g * ASTRIDE + 32 + ln] = wk[2];
    if (ln == 0) att_s[g * ASTRIDE + 48] = wk[3];
    if (!LAST) {
        const int gp = p * 2 + h;
        if (ln < 12)
            *(float4*)&cur[gp * ASTRIDE + ln * 4] =
                *(const float4*)&att_s[g * ASTRIDE + ln * 4];
        else if (ln == 12)
            cur[gp * ASTRIDE + 48] = att_s[g * ASTRIDE + 48];
    }
    __syncthreads();                                            // B2 (K reads done)
    // ---- phase 3: stage V-halo over K ----
    #pragma unroll
    for (int it = 0; it < 4; ++it) {
        int hp = it * 36 + (t >> 4);
        if (hp < HALO_N) {
            int c4 = (t & 15) << 2;
            *(float4*)&big[swz(hp, c4)] =
                *(const float4*)&qkv[halo_pix(hp, hr0, hc0) * QN + 128 + c4];
        }
    }
    __syncthreads();                                            // B3
    // ---- PV (LDS): lane owns dims {ln*2, ln*2+1} ----
    {
        const int vcol = h * 32 + ln * 2;
        float a0 = 0.f, a1 = 0.f;
        #pragma unroll
        for (int kk = 0; kk < 12; ++kk) {
            float4 w4 = *(const float4*)&att_s[g * ASTRIDE + kk * 4];
            #pragma unroll
            for (int c = 0; c < 4; ++c) {
                int n = kk * 4 + c;
                int a = n / 7, b = n % 7;        // compile-time after unroll
                float w = (c == 0) ? w4.x : (c == 1) ? w4.y : (c == 2) ? w4.z : w4.w;
                float2 v = *(const float2*)&big[swz(hbase + a * 11 + b, vcol)];
                a0 = fmaf(w, v.x, a0); a1 = fmaf(w, v.y, a1);
            }
        }
        float w48 = att_s[g * ASTRIDE + 48];
        float2 v48 = *(const float2*)&big[swz(hbase + 6 * 11 + 6, vcol)];
        a0 = fmaf(w48, v48.x, a0); a1 = fmaf(w48, v48.y, a1);
        *(float2*)&xs[swz(pl, vcol)] = make_float2(a0, a1);
    }
    __syncthreads();                                            // B4 (V reads done)
    // ---- phase 5: stage proj weights ----
    #pragma unroll
    for (int it = 0; it < 2; ++it) {
        int l = it * NT + t;
        if (l < 1024) {
            int j = l >> 4, cs = (l & 15) << 2;
            *(float4*)&big[swz(j, cs)] = *(const float4*)&pw[j * 64 + cs];
        }
    }
    __syncthreads();                                            // B5
    // ---- proj: pxg=t%9 (2 px), jo=t/9 (1 j) ----
    const int pxg = t % 9, jo = t / 9;
    float pa0 = pb[jo], pa1 = pa0;
    #pragma unroll
    for (int cc = 0; cc < 16; ++cc) {
        float4 xv0 = *(const float4*)&xs[swz(pxg * 2, cc * 4)];
        float4 xv1 = *(const float4*)&xs[swz(pxg * 2 + 1, cc * 4)];
        float4 wv  = *(const float4*)&big[swz(jo, cc * 4)];
        pa0 = fmaf(xv0.x, wv.x, pa0); pa0 = fmaf(xv0.y, wv.y, pa0);
        pa0 = fmaf(xv0.z, wv.z, pa0); pa0 = fmaf(xv0.w, wv.w, pa0);
        pa1 = fmaf(xv1.x, wv.x, pa1); pa1 = fmaf(xv1.y, wv.y, pa1);
        pa1 = fmaf(xv1.z, wv.z, pa1); pa1 = fmaf(xv1.w, wv.w, pa1);
    }
    __syncthreads();                                            // B6 (proj reads done)
    xs[swz(pxg * 2, jo)]     = pa0;
    xs[swz(pxg * 2 + 1, jo)] = pa1;
    if (!LAST) {
        #pragma unroll
        for (int it = 0; it < 6; ++it) {
            int l = it * NT + t;
            if (l < 3072) {
                int j = l >> 4, cs = (l & 15) << 2;
                *(float4*)&big[swz(j, cs)] = *(const float4*)&qw[j * 64 + cs];
            }
        }
    }
    __syncthreads();                                            // B7
    if (LAST) {
        #pragma unroll
        for (int it = 0; it < 2; ++it) {
            int l = it * NT + t;
            int px = l % 18, c = l / 18;
            outp[c * NPIX + (i0 + px / 3) * HW + j0c + px % 3] = xs[swz(px, c)];
        }
        return;
    }
    qkv_gemm(xs, big, qb, qkvn, i0, j0c, t);
}

extern "C" void kernel_launch(void* const* d_in, const int* in_sizes, int n_in,
                              void* d_out, int out_size, void* d_ws, size_t ws_size,
                              hipStream_t stream)
{
    const float* x   = (const float*)d_in[0];
    const float* qw  = (const float*)d_in[1];   // (3,192,64)
    const float* qb  = (const float*)d_in[2];   // (3,192)
    const float* pw  = (const float*)d_in[3];   // (3,64,64)
    const float* pb  = (const float*)d_in[4];   // (3,64)
    const float* rpb = (const float*)d_in[5];   // (3,2,13,13)
    float* out = (float*)d_out;
    float* ws  = (float*)d_ws;

    float* qkvA = ws;                    // 1,769,472 floats
    float* qkvB = qkvA + 1769472;        // 1,769,472
    float* attA = qkvB + 1769472;        //   958,464 (18432 * 52)
    float* attB = attA + 958464;         //   958,464  (~21.8 MB total)

    k_qkv0<<<512, NT, 0, stream>>>(x, qw, qb, qkvA);
    k_stage<0, 0><<<512, NT, 0, stream>>>(qkvA, rpb,       nullptr, attA,
                                          pw,        pb,       qw + 12288, qb + 192, qkvB, nullptr);
    k_stage<1, 0><<<512, NT, 0, stream>>>(qkvB, rpb + 338, attA,    attB,
                                          pw + 4096, pb + 64,  qw + 24576, qb + 384, qkvA, nullptr);
    k_stage<1, 1><<<512, NT, 0, stream>>>(qkvA, rpb + 676, attB,    nullptr,
                                          pw + 8192, pb + 128, nullptr,    nullptr,  nullptr, out);
}